// Round 9
// baseline (878.693 us; speedup 1.0000x reference)
//
#include <hip/hip_runtime.h>
#include <hip/hip_fp16.h>
#include <math.h>

#define N_NODES 50000
#define N_EDGES 800000
#define IN_C 96
#define HID_C 64
#define OUT_C 40
#define ALPHA 0.2f
#define NEG_SLOPE 0.01f
#define BKT_CAP 16384  // per (xcd,partition) sub-bucket capacity; mean 12.5k, 34 sigma margin

typedef _Float16 f16x8 __attribute__((ext_vector_type(8)));
typedef float f32x4 __attribute__((ext_vector_type(4)));

__device__ __forceinline__ int edge_at(const void* ei, int is64, long long pos) {
    return is64 ? (int)((const long long*)ei)[pos] : ((const int*)ei)[pos];
}

// ---------------- zero deg + tails + edge dtype detect (fused) ----------------
__global__ void zero_detect_k(int* deg, int n, int* tails, const unsigned int* ei, int* flag) {
    int i = blockIdx.x * blockDim.x + threadIdx.x;
    if (i < n) deg[i] = 0;
    if (i < 64) tails[i] = 0;
    if (i == 0) {
        int is64 = 1;
        for (int j = 1; j < 16; j += 2)
            if (ei[j] != 0u) is64 = 0;
        *flag = is64;
    }
}

// ---- phase A: single pass over edges: deg histogram + bin (s,d) into 64
// XCD-local sub-buckets (k = blockIdx%8 ~ XCD; p = dst partition).
// Tail bumps are wave-aggregated (<=8 atomics per wave-iter on 64 counters).
__global__ void bucketA_k(const void* ei, const int* flag, int* __restrict__ deg,
                          int* __restrict__ tails, int2* __restrict__ bkt, int E) {
    int k = blockIdx.x & 7;
    int per = (E + gridDim.x - 1) / gridDim.x;
    int e0 = blockIdx.x * per;
    int e1 = e0 + per; if (e1 > E) e1 = E;
    int f = *flag;
    int lane = threadIdx.x & 63;
    int iters = (e1 - e0 + blockDim.x - 1) / blockDim.x;
    for (int it = 0; it < iters; ++it) {
        int e = e0 + it * blockDim.x + threadIdx.x;
        bool act = e < e1;
        int s = 0, d = 0, p = 0;
        if (act) {
            d = edge_at(ei, f, (long long)E + e);
            s = edge_at(ei, f, e);
            p = d / (N_NODES / 8);
            if (p > 7) p = 7;
            atomicAdd(&deg[d], 1);
        }
        #pragma unroll
        for (int pp = 0; pp < 8; ++pp) {
            unsigned long long m = __ballot(act && p == pp);
            if (m == 0ull) continue;
            int leader = __ffsll((long long)m) - 1;
            int cnt = __popcll(m);
            int base = 0;
            if (lane == leader) base = atomicAdd(&tails[k * 8 + pp], cnt);
            base = __shfl(base, leader);
            if (act && p == pp) {
                int rank = __popcll(m & ((1ull << lane) - 1ull));
                int pos = base + rank;
                if (pos < BKT_CAP)
                    bkt[(size_t)(k * 8 + pp) * BKT_CAP + pos] = make_int2(s, d);
            }
        }
    }
}

// ---- parallel 3-phase exclusive scan over deg[n] ----
__global__ void scan_p1_k(const int* __restrict__ deg, int* __restrict__ part, int n) {
    __shared__ int sm[256];
    int t = threadIdx.x, i = blockIdx.x * 256 + t;
    int v = (i < n) ? deg[i] : 0;
    sm[t] = v;
    __syncthreads();
    for (int off = 1; off < 256; off <<= 1) {
        int u = (t >= off) ? sm[t - off] : 0;
        __syncthreads();
        sm[t] += u;
        __syncthreads();
    }
    if (t == 255) part[blockIdx.x] = sm[255];
}

__global__ void scan_p2_k(int* part, int nb, int* rowptr, int n) {
    __shared__ int sm[256];
    int t = threadIdx.x;
    int v = (t < nb) ? part[t] : 0;
    sm[t] = v;
    __syncthreads();
    for (int off = 1; off < 256; off <<= 1) {
        int u = (t >= off) ? sm[t - off] : 0;
        __syncthreads();
        sm[t] += u;
        __syncthreads();
    }
    if (t < nb) part[t] = sm[t] - v;  // exclusive
    if (t == 255) rowptr[n] = sm[255];
}

__global__ void scan_p3_k(const int* __restrict__ deg, const int* __restrict__ part,
                          int* __restrict__ rowptr, int* __restrict__ cursor,
                          float* __restrict__ dinv, int n) {
    __shared__ int sm[256];
    int t = threadIdx.x, i = blockIdx.x * 256 + t;
    int v = (i < n) ? deg[i] : 0;
    sm[t] = v;
    __syncthreads();
    for (int off = 1; off < 256; off <<= 1) {
        int u = (t >= off) ? sm[t - off] : 0;
        __syncthreads();
        sm[t] += u;
        __syncthreads();
    }
    if (i < n) {
        int excl = sm[t] - v + part[blockIdx.x];
        rowptr[i] = excl;
        cursor[i] = excl;
        dinv[i] = rsqrtf((float)v + 1.0f);  // +1 self loop
    }
}

// ---- phase B: scatter each partition's pairs into its csrc segment.
// blockIdx%8 = partition ~ XCD; segment (~400 KB) stays L2-resident.
__global__ void bucketB_k(const int* __restrict__ tails, const int2* __restrict__ bkt,
                          int* __restrict__ cursor, int* __restrict__ csrc) {
    int p = blockIdx.x & 7;
    int j = blockIdx.x >> 3;
    int J = gridDim.x >> 3;
    for (int k = 0; k < 8; ++k) {
        int n = tails[k * 8 + p];
        if (n > BKT_CAP) n = BKT_CAP;
        const int2* b = bkt + (size_t)(k * 8 + p) * BKT_CAP;
        for (int idx = j * blockDim.x + threadIdx.x; idx < n; idx += J * blockDim.x) {
            int2 e = b[idx];
            int pos = atomicAdd(&cursor[e.y], 1);
            csrc[pos] = e.x;
        }
    }
}

// ---------------- C=64 prop: quarter-wave per NODE ------------------------------
// 16-lane QW owns one node: lane ci holds channels [4ci,4ci+4) (8 B of the
// 128 B row) for the whole kernel -> no reductions, no idle lanes. The QW
// walks its own edge list 4-deep unrolled (wave = 4 nodes -> 16 rows in
// flight regardless of degree). G-space math as before.
template <bool COMBINE, bool LEAKY, bool BIAS>
__global__ void prop64_k(const int* __restrict__ rowptr, const int* __restrict__ csrc,
                         const float* __restrict__ dinv,
                         const __half* __restrict__ in, const __half* __restrict__ h0,
                         const float* __restrict__ bias,
                         __half* __restrict__ out, int N) {
    int node = blockIdx.x * (blockDim.x >> 4) + (threadIdx.x >> 4);
    int ci = threadIdx.x & 15;
    if (node >= N) return;
    const float2* in4 = (const float2*)in;  // 8 B = 4 halves (bit-carrier)
    f32x4 acc;
    {   // self-loop term G[node]
        float2 r = in4[node * 16 + ci];
        float2 a = __half22float2(*(const __half2*)&r.x);
        float2 b = __half22float2(*(const __half2*)&r.y);
        acc[0] = a.x; acc[1] = a.y; acc[2] = b.x; acc[3] = b.y;
    }
    int r0 = rowptr[node], r1 = rowptr[node + 1];
    int i = r0;
    for (; i + 3 < r1; i += 4) {  // 4 rows in flight per QW
        int s0 = csrc[i], s1 = csrc[i + 1], s2 = csrc[i + 2], s3 = csrc[i + 3];
        float2 v0 = in4[s0 * 16 + ci];
        float2 v1 = in4[s1 * 16 + ci];
        float2 v2 = in4[s2 * 16 + ci];
        float2 v3 = in4[s3 * 16 + ci];
        float2 a0 = __half22float2(*(const __half2*)&v0.x), b0 = __half22float2(*(const __half2*)&v0.y);
        float2 a1 = __half22float2(*(const __half2*)&v1.x), b1 = __half22float2(*(const __half2*)&v1.y);
        float2 a2 = __half22float2(*(const __half2*)&v2.x), b2 = __half22float2(*(const __half2*)&v2.y);
        float2 a3 = __half22float2(*(const __half2*)&v3.x), b3 = __half22float2(*(const __half2*)&v3.y);
        acc[0] += (a0.x + a1.x) + (a2.x + a3.x);
        acc[1] += (a0.y + a1.y) + (a2.y + a3.y);
        acc[2] += (b0.x + b1.x) + (b2.x + b3.x);
        acc[3] += (b0.y + b1.y) + (b2.y + b3.y);
    }
    for (; i < r1; ++i) {
        float2 v0 = in4[csrc[i] * 16 + ci];
        float2 a0 = __half22float2(*(const __half2*)&v0.x), b0 = __half22float2(*(const __half2*)&v0.y);
        acc[0] += a0.x; acc[1] += a0.y; acc[2] += b0.x; acc[3] += b0.y;
    }
    float di = dinv[node];
    float sc = di * di;
    float4 v;
    v.x = sc * acc[0]; v.y = sc * acc[1]; v.z = sc * acc[2]; v.w = sc * acc[3];
    if (BIAS) {
        const float4 b = ((const float4*)bias)[ci];
        v.x += di * b.x; v.y += di * b.y; v.z += di * b.z; v.w += di * b.w;
    }
    if (COMBINE) {
        float2 r = ((const float2*)h0)[node * 16 + ci];
        float2 a = __half22float2(*(const __half2*)&r.x);
        float2 b = __half22float2(*(const __half2*)&r.y);
        v.x = (1.0f - ALPHA) * v.x + ALPHA * a.x;
        v.y = (1.0f - ALPHA) * v.y + ALPHA * a.y;
        v.z = (1.0f - ALPHA) * v.z + ALPHA * b.x;
        v.w = (1.0f - ALPHA) * v.w + ALPHA * b.y;
    }
    if (LEAKY) {
        v.x = v.x > 0.0f ? v.x : NEG_SLOPE * v.x;
        v.y = v.y > 0.0f ? v.y : NEG_SLOPE * v.y;
        v.z = v.z > 0.0f ? v.z : NEG_SLOPE * v.z;
        v.w = v.w > 0.0f ? v.w : NEG_SLOPE * v.w;
    }
    float2 o;
    *(__half2*)&o.x = __float22half2_rn(make_float2(v.x, v.y));
    *(__half2*)&o.y = __float22half2_rn(make_float2(v.z, v.w));
    ((float2*)out)[node * 16 + ci] = o;
}

// ---------------- C=40 prop, half-wave scheme (conv4 first hop) ----------------
__global__ void prop40_k(const int* __restrict__ rowptr, const int* __restrict__ csrc,
                         const float* __restrict__ dinv,
                         const __half* __restrict__ in, __half* __restrict__ out, int N) {
    constexpr int CP = OUT_C / 2;  // 20
    int node = blockIdx.x * (blockDim.x >> 6) + (threadIdx.x >> 6);
    int lane = threadIdx.x & 63;
    int sub = lane >> 5;
    int ci = lane & 31;
    if (node >= N) return;
    bool act = ci < CP;
    const __half2* in2 = (const __half2*)in;
    float2 acc = make_float2(0.0f, 0.0f);
    if (sub == 0 && act) {
        float2 v = __half22float2(in2[(long long)node * CP + ci]);
        acc.x = v.x; acc.y = v.y;
    }
    int r0 = rowptr[node], r1 = rowptr[node + 1];
    int i = r0 + sub;
    for (; i + 6 < r1; i += 8) {
        int s0 = csrc[i], s1 = csrc[i + 2], s2 = csrc[i + 4], s3 = csrc[i + 6];
        if (act) {
            float2 v0 = __half22float2(in2[(long long)s0 * CP + ci]);
            float2 v1 = __half22float2(in2[(long long)s1 * CP + ci]);
            float2 v2 = __half22float2(in2[(long long)s2 * CP + ci]);
            float2 v3 = __half22float2(in2[(long long)s3 * CP + ci]);
            acc.x += (v0.x + v1.x) + (v2.x + v3.x);
            acc.y += (v0.y + v1.y) + (v2.y + v3.y);
        }
    }
    for (; i < r1; i += 2) {
        int s0 = csrc[i];
        if (act) {
            float2 v0 = __half22float2(in2[(long long)s0 * CP + ci]);
            acc.x += v0.x; acc.y += v0.y;
        }
    }
    acc.x += __shfl_xor(acc.x, 32);
    acc.y += __shfl_xor(acc.y, 32);
    if (sub == 0 && act) {
        float di = dinv[node];
        float sc = di * di;
        ((__half2*)out)[(long long)node * CP + ci] =
            __float22half2_rn(make_float2(sc * acc.x, sc * acc.y));
    }
}

// ---------------- final C=40 prop + b4 + log_softmax fused, fp32 out -----------
__global__ void prop40_softmax_k(const int* __restrict__ rowptr, const int* __restrict__ csrc,
                                 const float* __restrict__ dinv,
                                 const __half* __restrict__ in, const float* __restrict__ bias,
                                 float* __restrict__ out, int N) {
    constexpr int CP = OUT_C / 2;  // 20
    int node = blockIdx.x * (blockDim.x >> 6) + (threadIdx.x >> 6);
    int lane = threadIdx.x & 63;
    int sub = lane >> 5;
    int ci = lane & 31;
    if (node >= N) return;
    bool act = ci < CP;
    const __half2* in2 = (const __half2*)in;
    float2 acc = make_float2(0.0f, 0.0f);
    if (sub == 0 && act) {
        float2 v = __half22float2(in2[(long long)node * CP + ci]);
        acc.x = v.x; acc.y = v.y;
    }
    int r0 = rowptr[node], r1 = rowptr[node + 1];
    int i = r0 + sub;
    for (; i + 6 < r1; i += 8) {
        int s0 = csrc[i], s1 = csrc[i + 2], s2 = csrc[i + 4], s3 = csrc[i + 6];
        if (act) {
            float2 v0 = __half22float2(in2[(long long)s0 * CP + ci]);
            float2 v1 = __half22float2(in2[(long long)s1 * CP + ci]);
            float2 v2 = __half22float2(in2[(long long)s2 * CP + ci]);
            float2 v3 = __half22float2(in2[(long long)s3 * CP + ci]);
            acc.x += (v0.x + v1.x) + (v2.x + v3.x);
            acc.y += (v0.y + v1.y) + (v2.y + v3.y);
        }
    }
    for (; i < r1; i += 2) {
        int s0 = csrc[i];
        if (act) {
            float2 v0 = __half22float2(in2[(long long)s0 * CP + ci]);
            acc.x += v0.x; acc.y += v0.y;
        }
    }
    acc.x += __shfl_xor(acc.x, 32);
    acc.y += __shfl_xor(acc.y, 32);
    if (sub == 0) {
        float di = dinv[node];
        float2 v = make_float2(-INFINITY, -INFINITY);
        if (act) {
            v.x = di * acc.x + bias[2 * ci];
            v.y = di * acc.y + bias[2 * ci + 1];
        }
        float m = fmaxf(v.x, v.y);
        #pragma unroll
        for (int off = 16; off >= 1; off >>= 1) m = fmaxf(m, __shfl_xor(m, off));
        float e = act ? (expf(v.x - m) + expf(v.y - m)) : 0.0f;
        #pragma unroll
        for (int off = 16; off >= 1; off >>= 1) e += __shfl_xor(e, off);
        float ls = m + logf(e);
        if (act)
            ((float2*)out)[(long long)node * CP + ci] = make_float2(v.x - ls, v.y - ls);
    }
}

// ---------------- MFMA dense linear: out[m,o] = sum_k in[m,k]*W[o,k] -----------
template <int O, int K, bool FP32IN, bool SCALE>
__global__ void __launch_bounds__(256) mfma_lin_k(const void* __restrict__ in_,
                                                  const float* __restrict__ W,
                                                  const float* __restrict__ dinv,
                                                  __half* __restrict__ out, int Mtiles) {
    constexpr int P2 = 52;  // half2 pitch (104 halves = 208 B rows, 16B-aligned)
    __shared__ __half2 wsh[O * P2];
    for (int idx = threadIdx.x; idx < O * (K / 2); idx += 256) {
        int o = idx / (K / 2), kk = idx - o * (K / 2);
        float2 w2 = ((const float2*)W)[o * (K / 2) + kk];
        wsh[o * P2 + kk] = __floats2half2_rn(w2.x, w2.y);
    }
    __syncthreads();
    int wave = (blockIdx.x * 256 + threadIdx.x) >> 6;
    if (wave >= Mtiles) return;
    int lane = threadIdx.x & 63;
    int lm = lane & 15, q = lane >> 4;
    long long m0 = (long long)wave * 16;
    constexpr int NT = (O + 15) / 16;
    f32x4 acc[NT];
    #pragma unroll
    for (int j = 0; j < NT; ++j) acc[j] = (f32x4){0.f, 0.f, 0.f, 0.f};
    const __half* wsp = (const __half*)wsh;
    #pragma unroll
    for (int k0 = 0; k0 < K; k0 += 32) {
        f16x8 a;
        if (FP32IN) {
            const float* xr = (const float*)in_ + (m0 + lm) * K + k0 + q * 8;
            float4 x0 = ((const float4*)xr)[0];
            float4 x1 = ((const float4*)xr)[1];
            a = (f16x8){(_Float16)x0.x, (_Float16)x0.y, (_Float16)x0.z, (_Float16)x0.w,
                        (_Float16)x1.x, (_Float16)x1.y, (_Float16)x1.z, (_Float16)x1.w};
        } else {
            const __half* xr = (const __half*)in_ + (m0 + lm) * K + k0 + q * 8;
            a = *(const f16x8*)xr;
        }
        #pragma unroll
        for (int j = 0; j < NT; ++j) {
            f16x8 b = *(const f16x8*)(wsp + (16 * j + lm) * (2 * P2) + k0 + q * 8);
            acc[j] = __builtin_amdgcn_mfma_f32_16x16x32_f16(a, b, acc[j], 0, 0, 0);
        }
    }
    #pragma unroll
    for (int r = 0; r < 4; ++r) {
        long long m = m0 + q * 4 + r;
        float sc = SCALE ? dinv[m] : 1.0f;
        #pragma unroll
        for (int j = 0; j < NT; ++j) {
            int col = 16 * j + lm;
            if (col < O) out[m * O + col] = __float2half(acc[j][r] * sc);
        }
    }
}

// ---------------- launcher ----------------
static inline int cdiv(long long a, long long b) { return (int)((a + b - 1) / b); }
static inline size_t align256(size_t x) { return (x + 255) & ~(size_t)255; }

extern "C" void kernel_launch(void* const* d_in, const int* in_sizes, int n_in,
                              void* d_out, int out_size, void* d_ws, size_t ws_size,
                              hipStream_t stream) {
    const float* x  = (const float*)d_in[0];
    const void*  ei = d_in[1];
    const float* W0 = (const float*)d_in[2];
    const float* b0 = (const float*)d_in[3];
    const float* W4 = (const float*)d_in[4];
    const float* b4 = (const float*)d_in[5];
    float* out = (float*)d_out;

    const int N = N_NODES, E = N_EDGES;
    const int NB = cdiv(N, 256);
    char* ws = (char*)d_ws;
    int*    flag   = (int*)ws;     ws += 256;
    int*    deg    = (int*)ws;     ws += align256((size_t)N * 4);
    int*    rowptr = (int*)ws;     ws += align256((size_t)(N + 1) * 4);
    int*    cursor = (int*)ws;     ws += align256((size_t)N * 4);
    int*    part   = (int*)ws;     ws += align256(256 * 4);
    int*    tails  = (int*)ws;     ws += align256(64 * 4);
    float*  dinv   = (float*)ws;   ws += align256((size_t)N * 4);
    int*    csrc   = (int*)ws;     ws += align256((size_t)E * 4);
    __half* bufA   = (__half*)ws;  ws += align256((size_t)N * HID_C * 2);
    __half* bufB   = (__half*)ws;  ws += align256((size_t)N * HID_C * 2);
    __half* bufC   = (__half*)ws;  ws += align256((size_t)N * HID_C * 2);
    // sub-buckets alias bufA+bufB (8.39 MB <= 12.8 MB); used only before mfma_lin
    int2* bkt = (int2*)bufA;

    const int T = 256;
    const int MT = N / 16;           // 3125 MFMA tiles
    const int LB = cdiv(MT, 4);      // mfma_lin blocks (4 waves each)
    const int P64B = cdiv(N, T / 16);  // prop64 blocks (16 nodes each)
    const int NPB = T / 64;            // nodes per block, 40ch props

    // ---- CSR build (two-phase bucketed) ----
    zero_detect_k<<<cdiv(N, T), T, 0, stream>>>(deg, N, tails, (const unsigned int*)ei, flag);
    bucketA_k<<<1024, T, 0, stream>>>(ei, flag, deg, tails, bkt, E);
    scan_p1_k<<<NB, 256, 0, stream>>>(deg, part, N);
    scan_p2_k<<<1, 256, 0, stream>>>(part, NB, rowptr, N);
    scan_p3_k<<<NB, 256, 0, stream>>>(deg, part, rowptr, cursor, dinv, N);
    bucketB_k<<<8 * 32, T, 0, stream>>>(tails, bkt, cursor, csrc);

    // ---- conv0 (SGConv, K=2): linear folded first; output G-space ----
    mfma_lin_k<HID_C, IN_C, true, true><<<LB, 256, 0, stream>>>(x, W0, dinv, bufA, MT);
    prop64_k<false, false, false><<<P64B, T, 0, stream>>>(
        rowptr, csrc, dinv, bufA, nullptr, nullptr, bufB, N);
    prop64_k<false, false, true><<<P64B, T, 0, stream>>>(
        rowptr, csrc, dinv, bufB, nullptr, b0, bufC, N);  // + dinv*b0 -> Gh0

    // ---- conv1..conv3: leaky(APPNP(h)) entirely in G-space, Gh0 = bufC ----
    for (int r = 0; r < 3; ++r) {
        prop64_k<true, false, false><<<P64B, T, 0, stream>>>(
            rowptr, csrc, dinv, bufC, bufC, nullptr, bufB, N);
        // in-place bufC write safe: Gh0[node] read only by the QW writing it
        prop64_k<true, true, false><<<P64B, T, 0, stream>>>(
            rowptr, csrc, dinv, bufB, bufC, nullptr, bufC, N);
    }

    // ---- conv4 (SGConv, K=2): G-space lin (no scale), then 2 hops at 40ch ----
    mfma_lin_k<OUT_C, HID_C, false, false><<<LB, 256, 0, stream>>>(bufC, W4, dinv, bufA, MT);
    prop40_k<<<cdiv(N, NPB), T, 0, stream>>>(rowptr, csrc, dinv, bufA, bufB, N);
    prop40_softmax_k<<<cdiv(N, NPB), T, 0, stream>>>(rowptr, csrc, dinv, bufB, b4, out, N);
}

// Round 10
// 374.097 us; speedup vs baseline: 2.3488x; 2.3488x over previous
//
#include <hip/hip_runtime.h>
#include <hip/hip_fp16.h>
#include <math.h>

#define N_NODES 50000
#define N_EDGES 800000
#define IN_C 96
#define HID_C 64
#define OUT_C 40
#define ALPHA 0.2f
#define NEG_SLOPE 0.01f

typedef _Float16 f16x8 __attribute__((ext_vector_type(8)));
typedef float f32x4 __attribute__((ext_vector_type(4)));

__device__ __forceinline__ int edge_at(const void* ei, int is64, long long pos) {
    return is64 ? (int)((const long long*)ei)[pos] : ((const int*)ei)[pos];
}

// ---------------- zero deg + edge dtype detect (fused) ----------------
__global__ void zero_detect_k(int* deg, int n, const unsigned int* ei, int* flag) {
    int i = blockIdx.x * blockDim.x + threadIdx.x;
    if (i < n) deg[i] = 0;
    if (i == 0) {
        int is64 = 1;
        for (int j = 1; j < 16; j += 2)
            if (ei[j] != 0u) is64 = 0;
        *flag = is64;
    }
}

__global__ void deg_hist_k(const void* ei, const int* flag, int* deg, int E) {
    int e = blockIdx.x * blockDim.x + threadIdx.x;
    if (e < E) {
        int d = edge_at(ei, *flag, (long long)E + e);
        atomicAdd(&deg[d], 1);
    }
}

// ---- parallel 3-phase exclusive scan over deg[n] ----
__global__ void scan_p1_k(const int* __restrict__ deg, int* __restrict__ part, int n) {
    __shared__ int sm[256];
    int t = threadIdx.x, i = blockIdx.x * 256 + t;
    int v = (i < n) ? deg[i] : 0;
    sm[t] = v;
    __syncthreads();
    for (int off = 1; off < 256; off <<= 1) {
        int u = (t >= off) ? sm[t - off] : 0;
        __syncthreads();
        sm[t] += u;
        __syncthreads();
    }
    if (t == 255) part[blockIdx.x] = sm[255];
}

__global__ void scan_p2_k(int* part, int nb, int* rowptr, int n) {
    __shared__ int sm[256];
    int t = threadIdx.x;
    int v = (t < nb) ? part[t] : 0;
    sm[t] = v;
    __syncthreads();
    for (int off = 1; off < 256; off <<= 1) {
        int u = (t >= off) ? sm[t - off] : 0;
        __syncthreads();
        sm[t] += u;
        __syncthreads();
    }
    if (t < nb) part[t] = sm[t] - v;  // exclusive
    if (t == 255) rowptr[n] = sm[255];
}

__global__ void scan_p3_k(const int* __restrict__ deg, const int* __restrict__ part,
                          int* __restrict__ rowptr, int* __restrict__ cursor,
                          float* __restrict__ dinv, int n) {
    __shared__ int sm[256];
    int t = threadIdx.x, i = blockIdx.x * 256 + t;
    int v = (i < n) ? deg[i] : 0;
    sm[t] = v;
    __syncthreads();
    for (int off = 1; off < 256; off <<= 1) {
        int u = (t >= off) ? sm[t - off] : 0;
        __syncthreads();
        sm[t] += u;
        __syncthreads();
    }
    if (i < n) {
        int excl = sm[t] - v + part[blockIdx.x];
        rowptr[i] = excl;
        cursor[i] = excl;
        dinv[i] = rsqrtf((float)v + 1.0f);  // +1 self loop
    }
}

// fill CSR, XCD-partitioned: blockIdx%8 owns dst range [p*N/8,(p+1)*N/8).
// Plain (cached) loads: the dst stream is re-read by all 8 partitions -> L2 reuse.
#define FILL_CHUNK 8192
__global__ void csr_fill_k(const void* ei, const int* flag,
                           int* __restrict__ cursor, int* __restrict__ csrc,
                           int E, int N) {
    int p = blockIdx.x & 7;
    int chunk = blockIdx.x >> 3;
    int lo = p * (N / 8), hi = lo + (N / 8);  // 50000/8 = 6250 exact
    int e0 = chunk * FILL_CHUNK;
    int e1 = e0 + FILL_CHUNK; if (e1 > E) e1 = E;
    int f = *flag;
    for (int e = e0 + threadIdx.x; e < e1; e += blockDim.x) {
        int d = edge_at(ei, f, (long long)E + e);
        if (d >= lo && d < hi) {
            int s = edge_at(ei, f, e);
            int pos = atomicAdd(&cursor[d], 1);
            csrc[pos] = s;
        }
    }
}

// ---------------- C=64 prop: quarter-wave per NODE ------------------------------
// 16-lane QW owns one node: lane ci holds channels [4ci,4ci+4) (8 B of the
// 128 B row) end-to-end -> no reductions, no idle lanes. The QW walks its own
// edge list 4-deep unrolled (wave = 4 nodes -> 16 rows in flight regardless
// of degree). G-space math (G = dinv*h).
template <bool COMBINE, bool LEAKY, bool BIAS>
__global__ void prop64_k(const int* __restrict__ rowptr, const int* __restrict__ csrc,
                         const float* __restrict__ dinv,
                         const __half* __restrict__ in, const __half* __restrict__ h0,
                         const float* __restrict__ bias,
                         __half* __restrict__ out, int N) {
    int node = blockIdx.x * (blockDim.x >> 4) + (threadIdx.x >> 4);
    int ci = threadIdx.x & 15;
    if (node >= N) return;
    const float2* in4 = (const float2*)in;  // 8 B = 4 halves (bit-carrier)
    f32x4 acc;
    {   // self-loop term G[node]
        float2 r = in4[node * 16 + ci];
        float2 a = __half22float2(*(const __half2*)&r.x);
        float2 b = __half22float2(*(const __half2*)&r.y);
        acc[0] = a.x; acc[1] = a.y; acc[2] = b.x; acc[3] = b.y;
    }
    int r0 = rowptr[node], r1 = rowptr[node + 1];
    int i = r0;
    for (; i + 3 < r1; i += 4) {  // 4 rows in flight per QW
        int s0 = csrc[i], s1 = csrc[i + 1], s2 = csrc[i + 2], s3 = csrc[i + 3];
        float2 v0 = in4[s0 * 16 + ci];
        float2 v1 = in4[s1 * 16 + ci];
        float2 v2 = in4[s2 * 16 + ci];
        float2 v3 = in4[s3 * 16 + ci];
        float2 a0 = __half22float2(*(const __half2*)&v0.x), b0 = __half22float2(*(const __half2*)&v0.y);
        float2 a1 = __half22float2(*(const __half2*)&v1.x), b1 = __half22float2(*(const __half2*)&v1.y);
        float2 a2 = __half22float2(*(const __half2*)&v2.x), b2 = __half22float2(*(const __half2*)&v2.y);
        float2 a3 = __half22float2(*(const __half2*)&v3.x), b3 = __half22float2(*(const __half2*)&v3.y);
        acc[0] += (a0.x + a1.x) + (a2.x + a3.x);
        acc[1] += (a0.y + a1.y) + (a2.y + a3.y);
        acc[2] += (b0.x + b1.x) + (b2.x + b3.x);
        acc[3] += (b0.y + b1.y) + (b2.y + b3.y);
    }
    for (; i < r1; ++i) {
        float2 v0 = in4[csrc[i] * 16 + ci];
        float2 a0 = __half22float2(*(const __half2*)&v0.x), b0 = __half22float2(*(const __half2*)&v0.y);
        acc[0] += a0.x; acc[1] += a0.y; acc[2] += b0.x; acc[3] += b0.y;
    }
    float di = dinv[node];
    float sc = di * di;
    float4 v;
    v.x = sc * acc[0]; v.y = sc * acc[1]; v.z = sc * acc[2]; v.w = sc * acc[3];
    if (BIAS) {
        const float4 b = ((const float4*)bias)[ci];
        v.x += di * b.x; v.y += di * b.y; v.z += di * b.z; v.w += di * b.w;
    }
    if (COMBINE) {
        float2 r = ((const float2*)h0)[node * 16 + ci];
        float2 a = __half22float2(*(const __half2*)&r.x);
        float2 b = __half22float2(*(const __half2*)&r.y);
        v.x = (1.0f - ALPHA) * v.x + ALPHA * a.x;
        v.y = (1.0f - ALPHA) * v.y + ALPHA * a.y;
        v.z = (1.0f - ALPHA) * v.z + ALPHA * b.x;
        v.w = (1.0f - ALPHA) * v.w + ALPHA * b.y;
    }
    if (LEAKY) {
        v.x = v.x > 0.0f ? v.x : NEG_SLOPE * v.x;
        v.y = v.y > 0.0f ? v.y : NEG_SLOPE * v.y;
        v.z = v.z > 0.0f ? v.z : NEG_SLOPE * v.z;
        v.w = v.w > 0.0f ? v.w : NEG_SLOPE * v.w;
    }
    float2 o;
    *(__half2*)&o.x = __float22half2_rn(make_float2(v.x, v.y));
    *(__half2*)&o.y = __float22half2_rn(make_float2(v.z, v.w));
    ((float2*)out)[node * 16 + ci] = o;
}

// ---------------- C=40 prop: half-wave per NODE --------------------------------
// 32-lane group owns one node; lanes 0..19 each own one half2 channel pair
// end-to-end; walks the edge list 4-deep unrolled (no sub-split, no reduction).
__global__ void prop40_k(const int* __restrict__ rowptr, const int* __restrict__ csrc,
                         const float* __restrict__ dinv,
                         const __half* __restrict__ in, __half* __restrict__ out, int N) {
    constexpr int CP = OUT_C / 2;  // 20
    int node = blockIdx.x * (blockDim.x >> 5) + (threadIdx.x >> 5);
    int ci = threadIdx.x & 31;
    if (node >= N) return;
    bool act = ci < CP;
    const __half2* in2 = (const __half2*)in;
    float2 acc = make_float2(0.0f, 0.0f);
    if (act) {
        acc = __half22float2(in2[(long long)node * CP + ci]);
    }
    int r0 = rowptr[node], r1 = rowptr[node + 1];
    int i = r0;
    for (; i + 3 < r1; i += 4) {
        int s0 = csrc[i], s1 = csrc[i + 1], s2 = csrc[i + 2], s3 = csrc[i + 3];
        if (act) {
            float2 v0 = __half22float2(in2[(long long)s0 * CP + ci]);
            float2 v1 = __half22float2(in2[(long long)s1 * CP + ci]);
            float2 v2 = __half22float2(in2[(long long)s2 * CP + ci]);
            float2 v3 = __half22float2(in2[(long long)s3 * CP + ci]);
            acc.x += (v0.x + v1.x) + (v2.x + v3.x);
            acc.y += (v0.y + v1.y) + (v2.y + v3.y);
        }
    }
    for (; i < r1; ++i) {
        int s0 = csrc[i];
        if (act) {
            float2 v0 = __half22float2(in2[(long long)s0 * CP + ci]);
            acc.x += v0.x; acc.y += v0.y;
        }
    }
    if (act) {
        float di = dinv[node];
        float sc = di * di;
        ((__half2*)out)[(long long)node * CP + ci] =
            __float22half2_rn(make_float2(sc * acc.x, sc * acc.y));
    }
}

// ---------------- final C=40 prop + b4 + log_softmax fused, fp32 out -----------
// Half-wave per node, lanes own channels; softmax butterfly over the 32-lane
// group (inactive lanes contribute -INF / 0).
__global__ void prop40_softmax_k(const int* __restrict__ rowptr, const int* __restrict__ csrc,
                                 const float* __restrict__ dinv,
                                 const __half* __restrict__ in, const float* __restrict__ bias,
                                 float* __restrict__ out, int N) {
    constexpr int CP = OUT_C / 2;  // 20
    int node = blockIdx.x * (blockDim.x >> 5) + (threadIdx.x >> 5);
    int ci = threadIdx.x & 31;
    if (node >= N) return;
    bool act = ci < CP;
    const __half2* in2 = (const __half2*)in;
    float2 acc = make_float2(0.0f, 0.0f);
    if (act) {
        acc = __half22float2(in2[(long long)node * CP + ci]);
    }
    int r0 = rowptr[node], r1 = rowptr[node + 1];
    int i = r0;
    for (; i + 3 < r1; i += 4) {
        int s0 = csrc[i], s1 = csrc[i + 1], s2 = csrc[i + 2], s3 = csrc[i + 3];
        if (act) {
            float2 v0 = __half22float2(in2[(long long)s0 * CP + ci]);
            float2 v1 = __half22float2(in2[(long long)s1 * CP + ci]);
            float2 v2 = __half22float2(in2[(long long)s2 * CP + ci]);
            float2 v3 = __half22float2(in2[(long long)s3 * CP + ci]);
            acc.x += (v0.x + v1.x) + (v2.x + v3.x);
            acc.y += (v0.y + v1.y) + (v2.y + v3.y);
        }
    }
    for (; i < r1; ++i) {
        int s0 = csrc[i];
        if (act) {
            float2 v0 = __half22float2(in2[(long long)s0 * CP + ci]);
            acc.x += v0.x; acc.y += v0.y;
        }
    }
    float di = dinv[node];
    float2 v = make_float2(-INFINITY, -INFINITY);
    if (act) {
        v.x = di * acc.x + bias[2 * ci];
        v.y = di * acc.y + bias[2 * ci + 1];
    }
    float m = fmaxf(v.x, v.y);
    #pragma unroll
    for (int off = 16; off >= 1; off >>= 1) m = fmaxf(m, __shfl_xor(m, off));
    float e = act ? (expf(v.x - m) + expf(v.y - m)) : 0.0f;
    #pragma unroll
    for (int off = 16; off >= 1; off >>= 1) e += __shfl_xor(e, off);
    float ls = m + logf(e);
    if (act)
        ((float2*)out)[(long long)node * CP + ci] = make_float2(v.x - ls, v.y - ls);
}

// ---------------- MFMA dense linear: out[m,o] = sum_k in[m,k]*W[o,k] -----------
template <int O, int K, bool FP32IN, bool SCALE>
__global__ void __launch_bounds__(256) mfma_lin_k(const void* __restrict__ in_,
                                                  const float* __restrict__ W,
                                                  const float* __restrict__ dinv,
                                                  __half* __restrict__ out, int Mtiles) {
    constexpr int P2 = 52;  // half2 pitch (104 halves = 208 B rows, 16B-aligned)
    __shared__ __half2 wsh[O * P2];
    for (int idx = threadIdx.x; idx < O * (K / 2); idx += 256) {
        int o = idx / (K / 2), kk = idx - o * (K / 2);
        float2 w2 = ((const float2*)W)[o * (K / 2) + kk];
        wsh[o * P2 + kk] = __floats2half2_rn(w2.x, w2.y);
    }
    __syncthreads();
    int wave = (blockIdx.x * 256 + threadIdx.x) >> 6;
    if (wave >= Mtiles) return;
    int lane = threadIdx.x & 63;
    int lm = lane & 15, q = lane >> 4;
    long long m0 = (long long)wave * 16;
    constexpr int NT = (O + 15) / 16;
    f32x4 acc[NT];
    #pragma unroll
    for (int j = 0; j < NT; ++j) acc[j] = (f32x4){0.f, 0.f, 0.f, 0.f};
    const __half* wsp = (const __half*)wsh;
    #pragma unroll
    for (int k0 = 0; k0 < K; k0 += 32) {
        f16x8 a;
        if (FP32IN) {
            const float* xr = (const float*)in_ + (m0 + lm) * K + k0 + q * 8;
            float4 x0 = ((const float4*)xr)[0];
            float4 x1 = ((const float4*)xr)[1];
            a = (f16x8){(_Float16)x0.x, (_Float16)x0.y, (_Float16)x0.z, (_Float16)x0.w,
                        (_Float16)x1.x, (_Float16)x1.y, (_Float16)x1.z, (_Float16)x1.w};
        } else {
            const __half* xr = (const __half*)in_ + (m0 + lm) * K + k0 + q * 8;
            a = *(const f16x8*)xr;
        }
        #pragma unroll
        for (int j = 0; j < NT; ++j) {
            f16x8 b = *(const f16x8*)(wsp + (16 * j + lm) * (2 * P2) + k0 + q * 8);
            acc[j] = __builtin_amdgcn_mfma_f32_16x16x32_f16(a, b, acc[j], 0, 0, 0);
        }
    }
    #pragma unroll
    for (int r = 0; r < 4; ++r) {
        long long m = m0 + q * 4 + r;
        float sc = SCALE ? dinv[m] : 1.0f;
        #pragma unroll
        for (int j = 0; j < NT; ++j) {
            int col = 16 * j + lm;
            if (col < O) out[m * O + col] = __float2half(acc[j][r] * sc);
        }
    }
}

// ---------------- launcher ----------------
static inline int cdiv(long long a, long long b) { return (int)((a + b - 1) / b); }
static inline size_t align256(size_t x) { return (x + 255) & ~(size_t)255; }

extern "C" void kernel_launch(void* const* d_in, const int* in_sizes, int n_in,
                              void* d_out, int out_size, void* d_ws, size_t ws_size,
                              hipStream_t stream) {
    const float* x  = (const float*)d_in[0];
    const void*  ei = d_in[1];
    const float* W0 = (const float*)d_in[2];
    const float* b0 = (const float*)d_in[3];
    const float* W4 = (const float*)d_in[4];
    const float* b4 = (const float*)d_in[5];
    float* out = (float*)d_out;

    const int N = N_NODES, E = N_EDGES;
    const int NB = cdiv(N, 256);
    char* ws = (char*)d_ws;
    int*    flag   = (int*)ws;     ws += 256;
    int*    deg    = (int*)ws;     ws += align256((size_t)N * 4);
    int*    rowptr = (int*)ws;     ws += align256((size_t)(N + 1) * 4);
    int*    cursor = (int*)ws;     ws += align256((size_t)N * 4);
    int*    part   = (int*)ws;     ws += align256(256 * 4);
    float*  dinv   = (float*)ws;   ws += align256((size_t)N * 4);
    int*    csrc   = (int*)ws;     ws += align256((size_t)E * 4);
    __half* bufA   = (__half*)ws;  ws += align256((size_t)N * HID_C * 2);
    __half* bufB   = (__half*)ws;  ws += align256((size_t)N * HID_C * 2);
    __half* bufC   = (__half*)ws;  ws += align256((size_t)N * HID_C * 2);

    const int T = 256;
    const int MT = N / 16;             // 3125 MFMA tiles
    const int LB = cdiv(MT, 4);        // mfma_lin blocks (4 waves each)
    const int P64B = cdiv(N, T / 16);  // prop64 blocks (16 nodes each)
    const int P40B = cdiv(N, T / 32);  // prop40 blocks (8 nodes each)

    // ---- CSR build ----
    zero_detect_k<<<cdiv(N, T), T, 0, stream>>>(deg, N, (const unsigned int*)ei, flag);
    deg_hist_k<<<cdiv(E, T), T, 0, stream>>>(ei, flag, deg, E);
    scan_p1_k<<<NB, 256, 0, stream>>>(deg, part, N);
    scan_p2_k<<<1, 256, 0, stream>>>(part, NB, rowptr, N);
    scan_p3_k<<<NB, 256, 0, stream>>>(deg, part, rowptr, cursor, dinv, N);
    csr_fill_k<<<cdiv(E, FILL_CHUNK) * 8, T, 0, stream>>>(ei, flag, cursor, csrc, E, N);

    // ---- conv0 (SGConv, K=2): linear folded first; output G-space ----
    mfma_lin_k<HID_C, IN_C, true, true><<<LB, 256, 0, stream>>>(x, W0, dinv, bufA, MT);
    prop64_k<false, false, false><<<P64B, T, 0, stream>>>(
        rowptr, csrc, dinv, bufA, nullptr, nullptr, bufB, N);
    prop64_k<false, false, true><<<P64B, T, 0, stream>>>(
        rowptr, csrc, dinv, bufB, nullptr, b0, bufC, N);  // + dinv*b0 -> Gh0

    // ---- conv1..conv3: leaky(APPNP(h)) entirely in G-space, Gh0 = bufC ----
    for (int r = 0; r < 3; ++r) {
        prop64_k<true, false, false><<<P64B, T, 0, stream>>>(
            rowptr, csrc, dinv, bufC, bufC, nullptr, bufB, N);
        // in-place bufC write safe: Gh0[node] read only by the QW writing it
        prop64_k<true, true, false><<<P64B, T, 0, stream>>>(
            rowptr, csrc, dinv, bufB, bufC, nullptr, bufC, N);
    }

    // ---- conv4 (SGConv, K=2): G-space lin (no scale), then 2 hops at 40ch ----
    mfma_lin_k<OUT_C, HID_C, false, false><<<LB, 256, 0, stream>>>(bufC, W4, dinv, bufA, MT);
    prop40_k<<<P40B, T, 0, stream>>>(rowptr, csrc, dinv, bufA, bufB, N);
    prop40_softmax_k<<<P40B, T, 0, stream>>>(rowptr, csrc, dinv, bufB, b4, out, N);
}